// Round 1
// baseline (347.415 us; speedup 1.0000x reference)
//
#include <hip/hip_runtime.h>
#include <math.h>

#define T_DIM 4096
#define D_DIM 64

// ---------------------------------------------------------------------------
// Kernel 1: row-wise L2 normalize x and y (v / max(||v||, 1e-12)).
// One 64-lane wave per row (D=64 -> one element per lane).
// ---------------------------------------------------------------------------
__global__ void normalize_rows(const float* __restrict__ x, const float* __restrict__ y,
                               float* __restrict__ xn, float* __restrict__ yn,
                               int rows_per_tensor) {
    int gtid = blockIdx.x * blockDim.x + threadIdx.x;
    int row  = gtid >> 6;
    int lane = gtid & 63;
    const float* src;
    float* dst;
    if (row < rows_per_tensor) {
        src = x; dst = xn;
    } else {
        src = y; dst = yn; row -= rows_per_tensor;
    }
    size_t off = (size_t)row * D_DIM + lane;
    float v = src[off];
    float ss = v * v;
    #pragma unroll
    for (int o = 1; o < 64; o <<= 1) ss += __shfl_xor(ss, o);
    float inv = 1.0f / fmaxf(sqrtf(ss), 1e-12f);
    dst[off] = v * inv;
}

// ---------------------------------------------------------------------------
// Kernel 2: stable compaction of mask = im * sh per batch.
// One block (256 threads) per batch; Hillis-Steele scan over chunks of 256.
// idx[b*T + k] = k-th selected original index; cnt[b] = count.
// ---------------------------------------------------------------------------
__global__ void compact_mask(const int* __restrict__ im, const int* __restrict__ sh,
                             int* __restrict__ idx, int* __restrict__ cnt) {
    int b = blockIdx.x;
    __shared__ int s[256];
    __shared__ int s_base;
    if (threadIdx.x == 0) s_base = 0;
    __syncthreads();
    for (int chunk = 0; chunk < T_DIM; chunk += 256) {
        int t = chunk + threadIdx.x;
        int mv = im[(size_t)b * T_DIM + t] * sh[(size_t)b * T_DIM + t];
        s[threadIdx.x] = mv;
        __syncthreads();
        for (int o = 1; o < 256; o <<= 1) {
            int v = (threadIdx.x >= o) ? s[threadIdx.x - o] : 0;
            __syncthreads();
            s[threadIdx.x] += v;
            __syncthreads();
        }
        int incl = s[threadIdx.x];
        if (mv) idx[(size_t)b * T_DIM + s_base + incl - 1] = t;
        __syncthreads();
        if (threadIdx.x == 255) s_base += s[255];
        __syncthreads();
    }
    if (threadIdx.x == 0) cnt[b] = s_base;
}

// ---------------------------------------------------------------------------
// Kernel 3: main. One block per (col-tile of 64 selected cols, batch).
// Tiled 64x64 fp32 GEMM over selected rows with fused exp + column sums.
// sum_exp[c] = sum over all selected rows i of exp(10 * dot(xn[R_i], yn[C_c]))
// diag[c]    = 10 * dot(xn[R_{j0+c}], yn[C_{j0+c}])
// per[j] = log(sum_exp) - diag, summed over j < m, atomicAdd into partial[b].
// ---------------------------------------------------------------------------
__launch_bounds__(256)
__global__ void ntxent_main(const float* __restrict__ xn, const float* __restrict__ yn,
                            const int* __restrict__ Ridx, const int* __restrict__ Cidx,
                            const int* __restrict__ cnt, float* __restrict__ partial,
                            int B) {
    int b  = blockIdx.y;
    int nx = cnt[b];
    int ny = cnt[B + b];
    int m  = min(nx, ny);
    int j0 = blockIdx.x * 64;
    if (j0 >= m) return;

    __shared__ float As[64][68];   // +4 pad: keeps float4 16B alignment, breaks bank conflicts
    __shared__ float Bs[64][68];
    __shared__ float sum_exp[64];
    __shared__ float diag[64];
    __shared__ int   Cloc[64];

    int tid = threadIdx.x;
    if (tid < 64) {
        int j = j0 + tid;
        Cloc[tid]    = (j < ny) ? Cidx[(size_t)b * T_DIM + j] : 0;
        sum_exp[tid] = 0.0f;
        diag[tid]    = 0.0f;
    }
    __syncthreads();

    // Load B tile (64 selected col vectors) into LDS: 16 float4 per row
    for (int i = tid; i < 64 * 16; i += 256) {
        int c = i >> 4, kq = i & 15;
        float4 v = ((const float4*)(yn + ((size_t)b * T_DIM + Cloc[c]) * D_DIM))[kq];
        ((float4*)(&Bs[c][0]))[kq] = v;
    }

    int tx = tid & 15, ty = tid >> 4;
    int r0 = ty * 4, c0 = tx * 4;

    for (int i0 = 0; i0 < nx; i0 += 64) {
        // Load A tile (64 selected row vectors)
        for (int i = tid; i < 64 * 16; i += 256) {
            int r = i >> 4, kq = i & 15;
            int gi = i0 + r;
            int ri = (gi < nx) ? Ridx[(size_t)b * T_DIM + gi] : 0;
            float4 v = ((const float4*)(xn + ((size_t)b * T_DIM + ri) * D_DIM))[kq];
            ((float4*)(&As[r][0]))[kq] = v;
        }
        __syncthreads();

        float acc[4][4];
        #pragma unroll
        for (int i = 0; i < 4; i++)
            #pragma unroll
            for (int j = 0; j < 4; j++) acc[i][j] = 0.0f;

        #pragma unroll 16
        for (int k = 0; k < 64; k++) {
            float a0 = As[r0 + 0][k], a1 = As[r0 + 1][k];
            float a2 = As[r0 + 2][k], a3 = As[r0 + 3][k];
            float b0 = Bs[c0 + 0][k], b1 = Bs[c0 + 1][k];
            float b2 = Bs[c0 + 2][k], b3 = Bs[c0 + 3][k];
            acc[0][0] += a0 * b0; acc[0][1] += a0 * b1; acc[0][2] += a0 * b2; acc[0][3] += a0 * b3;
            acc[1][0] += a1 * b0; acc[1][1] += a1 * b1; acc[1][2] += a1 * b2; acc[1][3] += a1 * b3;
            acc[2][0] += a2 * b0; acc[2][1] += a2 * b1; acc[2][2] += a2 * b2; acc[2][3] += a2 * b3;
            acc[3][0] += a3 * b0; acc[3][1] += a3 * b1; acc[3][2] += a3 * b2; acc[3][3] += a3 * b3;
        }

        // exp + per-thread column partial sums (over this thread's 4 rows)
        float colsum[4];
        #pragma unroll
        for (int j = 0; j < 4; j++) {
            float cs = 0.0f;
            #pragma unroll
            for (int i = 0; i < 4; i++) {
                int grow = i0 + r0 + i;
                float sv = acc[i][j] * 10.0f;   // 1 / TEMPERATURE
                if (grow == j0 + c0 + j) diag[c0 + j] = sv;  // unique writer
                if (grow < nx) cs += __expf(sv);
            }
            colsum[j] = cs;
        }
        // reduce over the 4 ty values within each wave (lanes differ by 16, 32)
        #pragma unroll
        for (int j = 0; j < 4; j++) {
            colsum[j] += __shfl_xor(colsum[j], 16);
            colsum[j] += __shfl_xor(colsum[j], 32);
        }
        if ((tid & 63) < 16) {   // one lane per tx per wave
            #pragma unroll
            for (int j = 0; j < 4; j++) atomicAdd(&sum_exp[c0 + j], colsum[j]);
        }
        __syncthreads();
    }

    // per-column loss, block sum, accumulate per batch
    if (tid < 64) {
        int j = j0 + tid;
        float per = (j < m) ? (logf(sum_exp[tid]) - diag[tid]) : 0.0f;
        #pragma unroll
        for (int o = 32; o > 0; o >>= 1) per += __shfl_down(per, o);
        if (tid == 0) atomicAdd(&partial[b], per);
    }
}

// ---------------------------------------------------------------------------
// Kernel 4: finalize — mean over batches of partial[b] / m_b.
// ---------------------------------------------------------------------------
__global__ void finalize_loss(const float* __restrict__ partial, const int* __restrict__ cnt,
                              float* __restrict__ out, int B) {
    if (threadIdx.x == 0) {
        float acc = 0.0f;
        for (int b = 0; b < B; b++) {
            int mm = min(cnt[b], cnt[B + b]);
            if (mm > 0) acc += partial[b] / (float)mm;
        }
        out[0] = acc / (float)B;
    }
}

extern "C" void kernel_launch(void* const* d_in, const int* in_sizes, int n_in,
                              void* d_out, int out_size, void* d_ws, size_t ws_size,
                              hipStream_t stream) {
    const float* x  = (const float*)d_in[0];
    const float* y  = (const float*)d_in[1];
    const int* im1  = (const int*)d_in[2];
    const int* im2  = (const int*)d_in[3];
    const int* sh1  = (const int*)d_in[4];
    const int* sh2  = (const int*)d_in[5];

    int B = in_sizes[2] / T_DIM;          // B*T / T
    size_t nElem = (size_t)B * T_DIM * D_DIM;

    // workspace layout
    float* xn     = (float*)d_ws;
    float* yn     = xn + nElem;
    int*   Ridx   = (int*)(yn + nElem);
    int*   Cidx   = Ridx + (size_t)B * T_DIM;
    int*   cnt    = Cidx + (size_t)B * T_DIM;   // 2*B ints: nx then ny
    float* partial = (float*)(cnt + 2 * B);     // B floats

    hipMemsetAsync(partial, 0, B * sizeof(float), stream);

    int rows = B * T_DIM;
    int totalThreads = 2 * rows * 64;
    normalize_rows<<<totalThreads / 256, 256, 0, stream>>>(x, y, xn, yn, rows);

    compact_mask<<<B, 256, 0, stream>>>(im1, sh1, Ridx, cnt);
    compact_mask<<<B, 256, 0, stream>>>(im2, sh2, Cidx, cnt + B);

    dim3 grid(T_DIM / 64, B);
    ntxent_main<<<grid, 256, 0, stream>>>(xn, yn, Ridx, Cidx, cnt, partial, B);

    finalize_loss<<<1, 64, 0, stream>>>(partial, cnt, (float*)d_out, B);
}

// Round 2
// 168.480 us; speedup vs baseline: 2.0620x; 2.0620x over previous
//
#include <hip/hip_runtime.h>
#include <hip/hip_bf16.h>
#include <math.h>

#define T_DIM 4096
#define D_DIM 64

typedef short bfrag8 __attribute__((ext_vector_type(8)));   // 8 bf16 bits = 4 VGPRs
typedef float floatx4 __attribute__((ext_vector_type(4)));

// ---------------------------------------------------------------------------
// K1: row-wise L2 normalize; x additionally scaled by 1/TEMPERATURE=10.
// Output bf16 (RNE). One 64-lane wave per row (D=64 -> 1 elem/lane).
// ---------------------------------------------------------------------------
__global__ void normalize_rows(const float* __restrict__ x, const float* __restrict__ y,
                               __hip_bfloat16* __restrict__ xn, __hip_bfloat16* __restrict__ yn,
                               int rows_per_tensor) {
    int gtid = blockIdx.x * blockDim.x + threadIdx.x;
    int row  = gtid >> 6;
    int lane = gtid & 63;
    const float* src; __hip_bfloat16* dst; float scale;
    if (row < rows_per_tensor) { src = x; dst = xn; scale = 10.0f; }
    else { src = y; dst = yn; scale = 1.0f; row -= rows_per_tensor; }
    size_t off = (size_t)row * D_DIM + lane;
    float v = src[off];
    float ss = v * v;
    #pragma unroll
    for (int o = 1; o < 64; o <<= 1) ss += __shfl_xor(ss, o);
    float inv = scale / fmaxf(sqrtf(ss), 1e-12f);
    dst[off] = __float2bfloat16(v * inv);
}

// ---------------------------------------------------------------------------
// K2: stable compaction of mask = im*sh, ballot-based. One block per
// (batch, which). which==0 -> rows: writes Ridx, cnt[b], and float mask mxf.
// which==1 -> cols: writes Cidx, cnt[B+b].
// ---------------------------------------------------------------------------
__global__ void compact_mask(const int* __restrict__ im1, const int* __restrict__ sh1,
                             const int* __restrict__ im2, const int* __restrict__ sh2,
                             int* __restrict__ Ridx, int* __restrict__ Cidx,
                             float* __restrict__ mxf, int* __restrict__ cnt, int B) {
    int z = blockIdx.x;
    int which = z & 1, b = z >> 1;
    const int* im = which ? im2 : im1;
    const int* sh = which ? sh2 : sh1;
    int* idxout   = which ? Cidx : Ridx;

    __shared__ int wtot[4];
    __shared__ int sbase;
    int tid = threadIdx.x, w = tid >> 6, lane = tid & 63;
    if (tid == 0) sbase = 0;
    __syncthreads();

    for (int chunk = 0; chunk < T_DIM; chunk += 256) {
        int t = chunk + tid;
        int mv = im[(size_t)b * T_DIM + t] * sh[(size_t)b * T_DIM + t];
        unsigned long long bal = __ballot(mv != 0);
        int pre = __popcll(bal & ((1ull << lane) - 1ull));
        if (lane == 0) wtot[w] = __popcll(bal);
        __syncthreads();
        int off = sbase;
        for (int ww = 0; ww < w; ww++) off += wtot[ww];
        if (mv) idxout[(size_t)b * T_DIM + off + pre] = t;
        if (which == 0) mxf[(size_t)b * T_DIM + t] = (mv != 0) ? 1.0f : 0.0f;
        __syncthreads();
        if (tid == 0) sbase += wtot[0] + wtot[1] + wtot[2] + wtot[3];
        __syncthreads();
    }
    if (tid == 0) cnt[which * B + b] = sbase;
}

// ---------------------------------------------------------------------------
// K3: main. One block per (32-col tile of selected cols, batch); 4 waves.
// Streams ALL T rows (no gather): sum_exp[c] = sum_t mxf[t]*exp(sim[t][c]).
// sim computed by mfma_f32_16x16x32_bf16; x pre-scaled by 10 so sv = acc.
// diag[c] grabbed in-flight when original row t == Ridx[j].
// No __syncthreads inside the row loop.
// ---------------------------------------------------------------------------
__launch_bounds__(256)
__global__ void ntxent_main(const __hip_bfloat16* __restrict__ xn,
                            const __hip_bfloat16* __restrict__ yn,
                            const float* __restrict__ mxf,
                            const int* __restrict__ Ridx, const int* __restrict__ Cidx,
                            const int* __restrict__ cnt, float* __restrict__ partial,
                            int B) {
    int b  = blockIdx.y;
    int nx = cnt[b];
    int ny = cnt[B + b];
    int m  = min(nx, ny);
    int j0 = blockIdx.x * 32;
    if (j0 >= m) return;

    __shared__ __hip_bfloat16 Bs[32 * 72];   // 144B col stride: 2-way bank alias only (free)
    __shared__ float sum_exp[32];
    __shared__ float diag[32];
    __shared__ int   Cloc[32];
    __shared__ int   Rdg[32];

    int tid  = threadIdx.x;
    int wave = tid >> 6, lane = tid & 63, quad = lane >> 4, c16 = lane & 15;

    if (tid < 32) {
        int j = j0 + tid;
        Cloc[tid]    = (j < ny) ? Cidx[(size_t)b * T_DIM + j] : 0;
        Rdg[tid]     = (j < m)  ? Ridx[(size_t)b * T_DIM + j] : -1;
        sum_exp[tid] = 0.0f;
        diag[tid]    = 0.0f;
    }
    __syncthreads();

    // Stage B tile: 32 selected col vectors, 128B each (8x16B)
    {
        int c = tid >> 3, part = tid & 7;
        bfrag8 v = *reinterpret_cast<const bfrag8*>(
            yn + ((size_t)b * T_DIM + Cloc[c]) * D_DIM + part * 8);
        *reinterpret_cast<bfrag8*>(&Bs[c * 72 + part * 8]) = v;
    }
    __syncthreads();

    // B frags: fixed for the whole row loop. B[n=lane&15][k=quad*8+j]
    bfrag8 bf[2][2];
    #pragma unroll
    for (int cg = 0; cg < 2; cg++)
        #pragma unroll
        for (int kh = 0; kh < 2; kh++)
            bf[cg][kh] = *reinterpret_cast<const bfrag8*>(
                &Bs[(cg * 16 + c16) * 72 + kh * 32 + quad * 8]);

    int rd0 = Rdg[c16];
    int rd1 = Rdg[16 + c16];

    float csum0 = 0.0f, csum1 = 0.0f;
    const __hip_bfloat16* xb = xn + (size_t)b * T_DIM * D_DIM;
    const float* mb = mxf + (size_t)b * T_DIM;

    for (int i0 = 0; i0 < T_DIM; i0 += 64) {
        // A frag: A[m=lane&15][k=quad*8+j]; rows = i0 + wave*16 + m (coalesced)
        const __hip_bfloat16* arow = xb + (size_t)(i0 + wave * 16 + c16) * D_DIM;
        bfrag8 af0 = *reinterpret_cast<const bfrag8*>(arow + quad * 8);
        bfrag8 af1 = *reinterpret_cast<const bfrag8*>(arow + 32 + quad * 8);
        // mask for this lane's 4 output rows
        float4 mv = *reinterpret_cast<const float4*>(mb + i0 + wave * 16 + quad * 4);
        int tout = i0 + wave * 16 + quad * 4;

        floatx4 acc0 = {0.f, 0.f, 0.f, 0.f}, acc1 = {0.f, 0.f, 0.f, 0.f};
        acc0 = __builtin_amdgcn_mfma_f32_16x16x32_bf16(af0, bf[0][0], acc0, 0, 0, 0);
        acc0 = __builtin_amdgcn_mfma_f32_16x16x32_bf16(af1, bf[0][1], acc0, 0, 0, 0);
        acc1 = __builtin_amdgcn_mfma_f32_16x16x32_bf16(af0, bf[1][0], acc1, 0, 0, 0);
        acc1 = __builtin_amdgcn_mfma_f32_16x16x32_bf16(af1, bf[1][1], acc1, 0, 0, 0);

        // rare: capture diagonal (unique writer; execz-skipped when no lane matches)
        if (rd0 >= tout && rd0 <= tout + 3) {
            #pragma unroll
            for (int r = 0; r < 4; r++)
                if (tout + r == rd0) diag[c16] = acc0[r];
        }
        if (rd1 >= tout && rd1 <= tout + 3) {
            #pragma unroll
            for (int r = 0; r < 4; r++)
                if (tout + r == rd1) diag[16 + c16] = acc1[r];
        }

        float mvv[4] = {mv.x, mv.y, mv.z, mv.w};
        #pragma unroll
        for (int r = 0; r < 4; r++) {
            csum0 += mvv[r] * __expf(acc0[r]);
            csum1 += mvv[r] * __expf(acc1[r]);
        }
    }

    // reduce over quads (rows): lanes differing in bits 4,5 hold same column
    csum0 += __shfl_xor(csum0, 16); csum0 += __shfl_xor(csum0, 32);
    csum1 += __shfl_xor(csum1, 16); csum1 += __shfl_xor(csum1, 32);
    if (quad == 0) {
        atomicAdd(&sum_exp[c16], csum0);
        atomicAdd(&sum_exp[16 + c16], csum1);
    }
    __syncthreads();

    if (wave == 0) {
        int idx = lane & 31;
        int j = j0 + idx;
        float per = (lane < 32 && j < m) ? (logf(sum_exp[idx]) - diag[idx]) : 0.0f;
        #pragma unroll
        for (int o = 32; o > 0; o >>= 1) per += __shfl_xor(per, o);
        if (lane == 0) atomicAdd(&partial[b], per);
    }
}

// ---------------------------------------------------------------------------
// K4: finalize — mean over batches of partial[b] / m_b.
// ---------------------------------------------------------------------------
__global__ void finalize_loss(const float* __restrict__ partial, const int* __restrict__ cnt,
                              float* __restrict__ out, int B) {
    if (threadIdx.x == 0) {
        float acc = 0.0f;
        for (int b = 0; b < B; b++) {
            int mm = min(cnt[b], cnt[B + b]);
            if (mm > 0) acc += partial[b] / (float)mm;
        }
        out[0] = acc / (float)B;
    }
}

extern "C" void kernel_launch(void* const* d_in, const int* in_sizes, int n_in,
                              void* d_out, int out_size, void* d_ws, size_t ws_size,
                              hipStream_t stream) {
    const float* x  = (const float*)d_in[0];
    const float* y  = (const float*)d_in[1];
    const int* im1  = (const int*)d_in[2];
    const int* im2  = (const int*)d_in[3];
    const int* sh1  = (const int*)d_in[4];
    const int* sh2  = (const int*)d_in[5];

    int B = in_sizes[2] / T_DIM;
    size_t nElem = (size_t)B * T_DIM * D_DIM;

    // workspace layout (16B-aligned chunks)
    __hip_bfloat16* xn = (__hip_bfloat16*)d_ws;
    __hip_bfloat16* yn = xn + nElem;
    float* mxf  = (float*)(yn + nElem);
    int*   Ridx = (int*)(mxf + (size_t)B * T_DIM);
    int*   Cidx = Ridx + (size_t)B * T_DIM;
    int*   cnt  = Cidx + (size_t)B * T_DIM;     // 2*B ints
    float* partial = (float*)(cnt + 2 * B);     // B floats

    hipMemsetAsync(partial, 0, B * sizeof(float), stream);

    int rows = B * T_DIM;
    int totalThreads = 2 * rows * 64;
    normalize_rows<<<totalThreads / 256, 256, 0, stream>>>(x, y, xn, yn, rows);

    compact_mask<<<2 * B, 256, 0, stream>>>(im1, sh1, im2, sh2, Ridx, Cidx, mxf, cnt, B);

    dim3 grid(T_DIM / 32, B);
    ntxent_main<<<grid, 256, 0, stream>>>(xn, yn, mxf, Ridx, Cidx, cnt, partial, B);

    finalize_loss<<<1, 64, 0, stream>>>(partial, cnt, (float*)d_out, B);
}

// Round 3
// 132.244 us; speedup vs baseline: 2.6271x; 1.2740x over previous
//
#include <hip/hip_runtime.h>
#include <hip/hip_bf16.h>
#include <math.h>

#define T_DIM 4096
#define D_DIM 64
#define SPLITS 4
#define ROWS_PER_SPLIT (T_DIM / SPLITS)   // 1024
#define ITERS (ROWS_PER_SPLIT / 64)       // 16

typedef short bfrag8 __attribute__((ext_vector_type(8)));   // 8 bf16 = 4 VGPRs
typedef float floatx4 __attribute__((ext_vector_type(4)));

__device__ __forceinline__ float bf2f(unsigned short u) {
    return __uint_as_float(((unsigned int)u) << 16);
}

// ---------------------------------------------------------------------------
// K1: row-wise L2 normalize; x additionally scaled by 1/TEMPERATURE=10.
// ---------------------------------------------------------------------------
__global__ void normalize_rows(const float* __restrict__ x, const float* __restrict__ y,
                               __hip_bfloat16* __restrict__ xn, __hip_bfloat16* __restrict__ yn,
                               int rows_per_tensor) {
    int gtid = blockIdx.x * blockDim.x + threadIdx.x;
    int row  = gtid >> 6;
    int lane = gtid & 63;
    const float* src; __hip_bfloat16* dst; float scale;
    if (row < rows_per_tensor) { src = x; dst = xn; scale = 10.0f; }
    else { src = y; dst = yn; scale = 1.0f; row -= rows_per_tensor; }
    size_t off = (size_t)row * D_DIM + lane;
    float v = src[off];
    float ss = v * v;
    #pragma unroll
    for (int o = 1; o < 64; o <<= 1) ss += __shfl_xor(ss, o);
    float inv = scale / fmaxf(sqrtf(ss), 1e-12f);
    dst[off] = __float2bfloat16(v * inv);
}

// ---------------------------------------------------------------------------
// K2: stable compaction, 1024 threads/block, ballot-based. 2 barriers/chunk.
// ---------------------------------------------------------------------------
__global__ void compact_mask(const int* __restrict__ im1, const int* __restrict__ sh1,
                             const int* __restrict__ im2, const int* __restrict__ sh2,
                             int* __restrict__ Ridx, int* __restrict__ Cidx,
                             float* __restrict__ mxf, int* __restrict__ cnt, int B) {
    int z = blockIdx.x;
    int which = z & 1, b = z >> 1;
    const int* im = which ? im2 : im1;
    const int* sh = which ? sh2 : sh1;
    int* idxout   = which ? Cidx : Ridx;

    __shared__ int wtot[16];
    __shared__ int woff[16];
    __shared__ int sbase;
    int tid = threadIdx.x, w = tid >> 6, lane = tid & 63;
    if (tid == 0) sbase = 0;

    for (int chunk = 0; chunk < T_DIM; chunk += 1024) {
        int t = chunk + tid;
        int mv = im[(size_t)b * T_DIM + t] * sh[(size_t)b * T_DIM + t];
        unsigned long long bal = __ballot(mv != 0);
        int pre = __popcll(bal & ((1ull << lane) - 1ull));
        if (lane == 0) wtot[w] = __popcll(bal);
        __syncthreads();
        if (tid == 0) {
            int s = sbase;
            #pragma unroll
            for (int i = 0; i < 16; i++) { woff[i] = s; s += wtot[i]; }
            sbase = s;
        }
        __syncthreads();
        if (mv) idxout[(size_t)b * T_DIM + woff[w] + pre] = t;
        if (which == 0) mxf[(size_t)b * T_DIM + t] = (mv != 0) ? 1.0f : 0.0f;
    }
    __syncthreads();
    if (tid == 0) cnt[which * B + b] = sbase;
}

// ---------------------------------------------------------------------------
// K3: main. Grid (T/64 col-tiles, B, SPLITS row-splits); 256 thr / 4 waves.
// Streams 1024 rows per block: sum_exp[c] += sum_t mxf[t]*exp(sim[t][c]).
// Branch-free, software-prefetched inner loop; no diag capture.
// Partial col sums atomicAdd'ed into gsum[b*T + j].
// ---------------------------------------------------------------------------
__launch_bounds__(256)
__global__ void ntxent_main(const __hip_bfloat16* __restrict__ xn,
                            const __hip_bfloat16* __restrict__ yn,
                            const float* __restrict__ mxf,
                            const int* __restrict__ Cidx,
                            const int* __restrict__ cnt,
                            float* __restrict__ gsum, int B) {
    int b  = blockIdx.y;
    int nx = cnt[b];
    int ny = cnt[B + b];
    int m  = min(nx, ny);
    int j0 = blockIdx.x * 64;
    if (j0 >= m) return;
    int rbase = blockIdx.z * ROWS_PER_SPLIT;

    __shared__ __hip_bfloat16 Bs[64 * 72];   // row stride 144B (16B-aligned)
    __shared__ float sum_exp[64];
    __shared__ int   Cloc[64];

    int tid  = threadIdx.x;
    int wave = tid >> 6, lane = tid & 63, quad = lane >> 4, c16 = lane & 15;

    if (tid < 64) {
        int j = j0 + tid;
        Cloc[tid]    = (j < ny) ? Cidx[(size_t)b * T_DIM + j] : 0;
        sum_exp[tid] = 0.0f;
    }
    __syncthreads();

    // Stage B tile: 64 col vectors x 128B = 8 KB
    #pragma unroll
    for (int i = tid; i < 64 * 8; i += 256) {
        int c = i >> 3, part = i & 7;
        bfrag8 v = *reinterpret_cast<const bfrag8*>(
            yn + ((size_t)b * T_DIM + Cloc[c]) * D_DIM + part * 8);
        *reinterpret_cast<bfrag8*>(&Bs[c * 72 + part * 8]) = v;
    }
    __syncthreads();

    // B frags: fixed for whole loop. B[n=lane&15][k=quad*8+e]
    bfrag8 bf[4][2];
    #pragma unroll
    for (int cg = 0; cg < 4; cg++)
        #pragma unroll
        for (int kh = 0; kh < 2; kh++)
            bf[cg][kh] = *reinterpret_cast<const bfrag8*>(
                &Bs[(cg * 16 + c16) * 72 + kh * 32 + quad * 8]);

    const __hip_bfloat16* xb = xn + (size_t)b * T_DIM * D_DIM;
    const float* mb = mxf + (size_t)b * T_DIM;

    float csum[4] = {0.f, 0.f, 0.f, 0.f};

    // prefetch iter 0: this wave's 16 rows at rbase + wave*16
    const __hip_bfloat16* arow = xb + (size_t)(rbase + wave * 16 + c16) * D_DIM;
    bfrag8 af0 = *reinterpret_cast<const bfrag8*>(arow + quad * 8);
    bfrag8 af1 = *reinterpret_cast<const bfrag8*>(arow + 32 + quad * 8);
    float4 mv  = *reinterpret_cast<const float4*>(mb + rbase + wave * 16 + quad * 4);

    for (int it = 0; it < ITERS; it++) {
        // prefetch next iteration (wraps to it=0 on last iter; discarded)
        int it1 = (it + 1) & (ITERS - 1);
        const __hip_bfloat16* narow =
            xb + (size_t)(rbase + it1 * 64 + wave * 16 + c16) * D_DIM;
        bfrag8 naf0 = *reinterpret_cast<const bfrag8*>(narow + quad * 8);
        bfrag8 naf1 = *reinterpret_cast<const bfrag8*>(narow + 32 + quad * 8);
        float4 nmv  = *reinterpret_cast<const float4*>(
            mb + rbase + it1 * 64 + wave * 16 + quad * 4);

        float mvv[4] = {mv.x, mv.y, mv.z, mv.w};
        #pragma unroll
        for (int cg = 0; cg < 4; cg++) {
            floatx4 acc = {0.f, 0.f, 0.f, 0.f};
            acc = __builtin_amdgcn_mfma_f32_16x16x32_bf16(af0, bf[cg][0], acc, 0, 0, 0);
            acc = __builtin_amdgcn_mfma_f32_16x16x32_bf16(af1, bf[cg][1], acc, 0, 0, 0);
            #pragma unroll
            for (int r = 0; r < 4; r++)
                csum[cg] += mvv[r] * __expf(acc[r]);
        }
        af0 = naf0; af1 = naf1; mv = nmv;
    }

    // reduce over quads (rows): lanes differing in bits 4,5 hold same column
    #pragma unroll
    for (int cg = 0; cg < 4; cg++) {
        csum[cg] += __shfl_xor(csum[cg], 16);
        csum[cg] += __shfl_xor(csum[cg], 32);
    }
    if (lane < 16) {
        #pragma unroll
        for (int cg = 0; cg < 4; cg++)
            atomicAdd(&sum_exp[cg * 16 + c16], csum[cg]);
    }
    __syncthreads();

    if (tid < 64)
        atomicAdd(&gsum[(size_t)b * T_DIM + j0 + tid], sum_exp[tid]);
}

// ---------------------------------------------------------------------------
// K4: per-column loss. 16-lane group per column j: diag = 10*dot recomputed
// exactly from bf16 xn (pre-scaled), per = log(gsum) - diag; block-reduce,
// one atomicAdd per active block into partial[b].
// ---------------------------------------------------------------------------
__global__ void per_col_loss(const __hip_bfloat16* __restrict__ xn,
                             const __hip_bfloat16* __restrict__ yn,
                             const float* __restrict__ gsum,
                             const int* __restrict__ Ridx, const int* __restrict__ Cidx,
                             const int* __restrict__ cnt,
                             float* __restrict__ partial, int B) {
    int b  = blockIdx.y;
    int nx = cnt[b];
    int ny = cnt[B + b];
    int m  = min(nx, ny);
    if (blockIdx.x * 16 >= m) return;

    int tid = threadIdx.x, wave = tid >> 6, lane = tid & 63;
    int g = tid >> 4, l = tid & 15;
    int j = blockIdx.x * 16 + g;

    float per = 0.0f;
    if (j < m) {
        int rj = Ridx[(size_t)b * T_DIM + j];
        int cj = Cidx[(size_t)b * T_DIM + j];
        const unsigned short* xa =
            (const unsigned short*)(xn + ((size_t)b * T_DIM + rj) * D_DIM) + l * 4;
        const unsigned short* yc =
            (const unsigned short*)(yn + ((size_t)b * T_DIM + cj) * D_DIM) + l * 4;
        float d = 0.0f;
        #pragma unroll
        for (int e = 0; e < 4; e++) d += bf2f(xa[e]) * bf2f(yc[e]);
        #pragma unroll
        for (int o = 1; o < 16; o <<= 1) d += __shfl_xor(d, o);
        per = (l == 0) ? (logf(gsum[(size_t)b * T_DIM + j]) - d) : 0.0f;
    }
    // full-wave sum (non-leader lanes contribute 0), then cross-wave via LDS
    #pragma unroll
    for (int o = 1; o < 64; o <<= 1) per += __shfl_xor(per, o);
    __shared__ float ws[4];
    if (lane == 0) ws[wave] = per;
    __syncthreads();
    if (tid == 0) atomicAdd(&partial[b], ws[0] + ws[1] + ws[2] + ws[3]);
}

// ---------------------------------------------------------------------------
// K5: finalize — mean over batches of partial[b] / m_b.
// ---------------------------------------------------------------------------
__global__ void finalize_loss(const float* __restrict__ partial, const int* __restrict__ cnt,
                              float* __restrict__ out, int B) {
    if (threadIdx.x == 0) {
        float acc = 0.0f;
        for (int b = 0; b < B; b++) {
            int mm = min(cnt[b], cnt[B + b]);
            if (mm > 0) acc += partial[b] / (float)mm;
        }
        out[0] = acc / (float)B;
    }
}

extern "C" void kernel_launch(void* const* d_in, const int* in_sizes, int n_in,
                              void* d_out, int out_size, void* d_ws, size_t ws_size,
                              hipStream_t stream) {
    const float* x  = (const float*)d_in[0];
    const float* y  = (const float*)d_in[1];
    const int* im1  = (const int*)d_in[2];
    const int* im2  = (const int*)d_in[3];
    const int* sh1  = (const int*)d_in[4];
    const int* sh2  = (const int*)d_in[5];

    int B = in_sizes[2] / T_DIM;
    size_t nElem = (size_t)B * T_DIM * D_DIM;

    // workspace layout (16B-aligned chunks)
    __hip_bfloat16* xn = (__hip_bfloat16*)d_ws;
    __hip_bfloat16* yn = xn + nElem;
    float* mxf  = (float*)(yn + nElem);
    float* gsum = mxf + (size_t)B * T_DIM;           // B*T floats
    float* partial = gsum + (size_t)B * T_DIM;       // B floats
    int*   Ridx = (int*)(partial + B);
    int*   Cidx = Ridx + (size_t)B * T_DIM;
    int*   cnt  = Cidx + (size_t)B * T_DIM;          // 2*B ints

    // zero gsum + partial in one shot (contiguous)
    hipMemsetAsync(gsum, 0, ((size_t)B * T_DIM + B) * sizeof(float), stream);

    int rows = B * T_DIM;
    int totalThreads = 2 * rows * 64;
    normalize_rows<<<totalThreads / 256, 256, 0, stream>>>(x, y, xn, yn, rows);

    compact_mask<<<2 * B, 1024, 0, stream>>>(im1, sh1, im2, sh2, Ridx, Cidx, mxf, cnt, B);

    dim3 grid(T_DIM / 64, B, SPLITS);
    ntxent_main<<<grid, 256, 0, stream>>>(xn, yn, mxf, Cidx, cnt, gsum, B);

    dim3 grid2(T_DIM / 16, B);
    per_col_loss<<<grid2, 256, 0, stream>>>(xn, yn, gsum, Ridx, Cidx, cnt, partial, B);

    finalize_loss<<<1, 64, 0, stream>>>(partial, cnt, (float*)d_out, B);
}

// Round 4
// 120.616 us; speedup vs baseline: 2.8803x; 1.0964x over previous
//
#include <hip/hip_runtime.h>
#include <hip/hip_bf16.h>
#include <math.h>

#define T_DIM 4096
#define D_DIM 64
#define SPLITS 8
#define ROWS_PER_SPLIT (T_DIM / SPLITS)   // 512
#define ITERS (ROWS_PER_SPLIT / 64)       // 8
#define SCALE_X 14.4269504088896340736f   // (1/TEMPERATURE) * log2(e): exp(10 s) = exp2(14.427 s)
#define LN2 0.69314718055994530942f

typedef short bfrag8 __attribute__((ext_vector_type(8)));   // 8 bf16 = 4 VGPRs
typedef float floatx4 __attribute__((ext_vector_type(4)));

__device__ __forceinline__ float bf2f(unsigned short u) {
    return __uint_as_float(((unsigned int)u) << 16);
}

// ---------------------------------------------------------------------------
// K1 "prep": fused normalize (blocks [0, normBlocks)) + mask compaction +
// gsum/out zeroing (blocks [normBlocks, normBlocks+2B)).
// Normalize: 16 rows/block, 16 lanes/row, float4 loads, ushort4 stores.
// x rows scaled by SCALE_X (folds 1/T and log2e into the bf16 cast).
// ---------------------------------------------------------------------------
__launch_bounds__(256)
__global__ void prep(const float* __restrict__ x, const float* __restrict__ y,
                     const int* __restrict__ im1, const int* __restrict__ sh1,
                     const int* __restrict__ im2, const int* __restrict__ sh2,
                     __hip_bfloat16* __restrict__ xn, __hip_bfloat16* __restrict__ yn,
                     float* __restrict__ mxf, int* __restrict__ Ridx, int* __restrict__ Cidx,
                     int* __restrict__ cnt, float* __restrict__ gsum, float* __restrict__ out,
                     int rows, int normBlocks, int B) {
    int tid = threadIdx.x;
    if ((int)blockIdx.x < normBlocks) {
        int row = blockIdx.x * 16 + (tid >> 4);
        int l = tid & 15;
        const float* src; __hip_bfloat16* dst; float scale;
        if (row < rows) { src = x; dst = xn; scale = SCALE_X; }
        else { src = y; dst = yn; scale = 1.0f; row -= rows; }
        size_t off = (size_t)row * D_DIM + l * 4;
        float4 v = *reinterpret_cast<const float4*>(src + off);
        float ss = v.x * v.x + v.y * v.y + v.z * v.z + v.w * v.w;
        #pragma unroll
        for (int o = 1; o < 16; o <<= 1) ss += __shfl_xor(ss, o);
        float inv = scale / fmaxf(sqrtf(ss), 1e-12f);
        __hip_bfloat16 h0 = __float2bfloat16(v.x * inv);
        __hip_bfloat16 h1 = __float2bfloat16(v.y * inv);
        __hip_bfloat16 h2 = __float2bfloat16(v.z * inv);
        __hip_bfloat16 h3 = __float2bfloat16(v.w * inv);
        ushort4 o4;
        o4.x = *reinterpret_cast<unsigned short*>(&h0);
        o4.y = *reinterpret_cast<unsigned short*>(&h1);
        o4.z = *reinterpret_cast<unsigned short*>(&h2);
        o4.w = *reinterpret_cast<unsigned short*>(&h3);
        *reinterpret_cast<ushort4*>((unsigned short*)dst + off) = o4;
    } else {
        int z = blockIdx.x - normBlocks;
        int which = z & 1, b = z >> 1;
        const int* im = which ? im2 : im1;
        const int* sh = which ? sh2 : sh1;
        int* idxout   = which ? Cidx : Ridx;

        __shared__ int wtot[4], woff[4];
        __shared__ int sbase;
        int w = tid >> 6, lane = tid & 63;
        if (tid == 0) sbase = 0;

        for (int chunk = 0; chunk < T_DIM; chunk += 256) {
            int t = chunk + tid;
            int mv = im[(size_t)b * T_DIM + t] * sh[(size_t)b * T_DIM + t];
            unsigned long long bal = __ballot(mv != 0);
            int pre = __popcll(bal & ((1ull << lane) - 1ull));
            if (lane == 0) wtot[w] = __popcll(bal);
            __syncthreads();
            if (tid == 0) {
                int s = sbase;
                #pragma unroll
                for (int i = 0; i < 4; i++) { woff[i] = s; s += wtot[i]; }
                sbase = s;
            }
            __syncthreads();
            if (mv) idxout[(size_t)b * T_DIM + woff[w] + pre] = t;
            if (which == 0) mxf[(size_t)b * T_DIM + t] = (mv != 0) ? 1.0f : 0.0f;
        }
        __syncthreads();
        if (tid == 0) cnt[which * B + b] = sbase;
        if (which == 0) {
            for (int i = tid; i < T_DIM; i += 256) gsum[(size_t)b * T_DIM + i] = 0.0f;
            if (z == 0 && tid == 0) out[0] = 0.0f;
        }
    }
}

// ---------------------------------------------------------------------------
// K2 main: grid (T/64 col-tiles, B, 8 row-splits); 256 thr / 4 waves.
// Streams 512 rows/block: gsum[c] += sum_t mxf[t]*exp2(sim2[t][c]) where
// sim2 = sim * 10*log2e (folded into xn). Branch-free, prefetched, raw
// v_exp_f32 in inner loop.
// ---------------------------------------------------------------------------
__launch_bounds__(256)
__global__ void ntxent_main(const __hip_bfloat16* __restrict__ xn,
                            const __hip_bfloat16* __restrict__ yn,
                            const float* __restrict__ mxf,
                            const int* __restrict__ Cidx,
                            const int* __restrict__ cnt,
                            float* __restrict__ gsum, int B) {
    int b  = blockIdx.y;
    int ny = cnt[B + b];
    int m  = min(cnt[b], ny);
    int j0 = blockIdx.x * 64;
    if (j0 >= m) return;
    int rbase = blockIdx.z * ROWS_PER_SPLIT;

    __shared__ __hip_bfloat16 Bs[64 * 72];   // row stride 144B
    __shared__ float sum_exp[64];
    __shared__ int   Cloc[64];

    int tid  = threadIdx.x;
    int wave = tid >> 6, lane = tid & 63, quad = lane >> 4, c16 = lane & 15;

    if (tid < 64) {
        int j = j0 + tid;
        Cloc[tid]    = (j < ny) ? Cidx[(size_t)b * T_DIM + j] : 0;
        sum_exp[tid] = 0.0f;
    }
    __syncthreads();

    // Stage B tile: 64 col vectors x 128B
    #pragma unroll
    for (int i = tid; i < 64 * 8; i += 256) {
        int c = i >> 3, part = i & 7;
        bfrag8 v = *reinterpret_cast<const bfrag8*>(
            yn + ((size_t)b * T_DIM + Cloc[c]) * D_DIM + part * 8);
        *reinterpret_cast<bfrag8*>(&Bs[c * 72 + part * 8]) = v;
    }
    __syncthreads();

    bfrag8 bf[4][2];
    #pragma unroll
    for (int cg = 0; cg < 4; cg++)
        #pragma unroll
        for (int kh = 0; kh < 2; kh++)
            bf[cg][kh] = *reinterpret_cast<const bfrag8*>(
                &Bs[(cg * 16 + c16) * 72 + kh * 32 + quad * 8]);

    const __hip_bfloat16* xb = xn + (size_t)b * T_DIM * D_DIM;
    const float* mb = mxf + (size_t)b * T_DIM;

    float csum[4] = {0.f, 0.f, 0.f, 0.f};

    const __hip_bfloat16* arow = xb + (size_t)(rbase + wave * 16 + c16) * D_DIM;
    bfrag8 af0 = *reinterpret_cast<const bfrag8*>(arow + quad * 8);
    bfrag8 af1 = *reinterpret_cast<const bfrag8*>(arow + 32 + quad * 8);
    float4 mv  = *reinterpret_cast<const float4*>(mb + rbase + wave * 16 + quad * 4);

    for (int it = 0; it < ITERS; it++) {
        int it1 = (it + 1) & (ITERS - 1);
        const __hip_bfloat16* narow =
            xb + (size_t)(rbase + it1 * 64 + wave * 16 + c16) * D_DIM;
        bfrag8 naf0 = *reinterpret_cast<const bfrag8*>(narow + quad * 8);
        bfrag8 naf1 = *reinterpret_cast<const bfrag8*>(narow + 32 + quad * 8);
        float4 nmv  = *reinterpret_cast<const float4*>(
            mb + rbase + it1 * 64 + wave * 16 + quad * 4);

        float mvv[4] = {mv.x, mv.y, mv.z, mv.w};
        #pragma unroll
        for (int cg = 0; cg < 4; cg++) {
            floatx4 acc = {0.f, 0.f, 0.f, 0.f};
            acc = __builtin_amdgcn_mfma_f32_16x16x32_bf16(af0, bf[cg][0], acc, 0, 0, 0);
            acc = __builtin_amdgcn_mfma_f32_16x16x32_bf16(af1, bf[cg][1], acc, 0, 0, 0);
            #pragma unroll
            for (int r = 0; r < 4; r++)
                csum[cg] += mvv[r] * exp2f(acc[r]);
        }
        af0 = naf0; af1 = naf1; mv = nmv;
    }

    #pragma unroll
    for (int cg = 0; cg < 4; cg++) {
        csum[cg] += __shfl_xor(csum[cg], 16);
        csum[cg] += __shfl_xor(csum[cg], 32);
    }
    if (lane < 16) {
        #pragma unroll
        for (int cg = 0; cg < 4; cg++)
            atomicAdd(&sum_exp[cg * 16 + c16], csum[cg]);
    }
    __syncthreads();

    if (tid < 64)
        atomicAdd(&gsum[(size_t)b * T_DIM + j0 + tid], sum_exp[tid]);
}

// ---------------------------------------------------------------------------
// K3: per-column loss + final mean. 16 blocks/batch; each 16-lane group does
// one column per round: diag2 = dot(xn,yn) (log2 units), per = ln2*(log2(g)-d2).
// Block sum / (m*B) atomicAdd'ed into out[0] (zeroed in prep).
// ---------------------------------------------------------------------------
__launch_bounds__(256)
__global__ void per_col_loss(const __hip_bfloat16* __restrict__ xn,
                             const __hip_bfloat16* __restrict__ yn,
                             const float* __restrict__ gsum,
                             const int* __restrict__ Ridx, const int* __restrict__ Cidx,
                             const int* __restrict__ cnt,
                             float* __restrict__ out, int B) {
    int b  = blockIdx.y;
    int m  = min(cnt[b], cnt[B + b]);
    if (m <= 0) return;

    int tid = threadIdx.x, wave = tid >> 6, lane = tid & 63;
    int g = tid >> 4, l = tid & 15;

    float acc = 0.0f;
    for (int j = blockIdx.x * 16 + g; j < m; j += 16 * gridDim.x) {
        int rj = Ridx[(size_t)b * T_DIM + j];
        int cj = Cidx[(size_t)b * T_DIM + j];
        const unsigned short* xa =
            (const unsigned short*)(xn + ((size_t)b * T_DIM + rj) * D_DIM) + l * 4;
        const unsigned short* yc =
            (const unsigned short*)(yn + ((size_t)b * T_DIM + cj) * D_DIM) + l * 4;
        float d = 0.0f;
        #pragma unroll
        for (int e = 0; e < 4; e++) d += bf2f(xa[e]) * bf2f(yc[e]);
        #pragma unroll
        for (int o = 1; o < 16; o <<= 1) d += __shfl_xor(d, o);
        if (l == 0) acc += LN2 * (__log2f(gsum[(size_t)b * T_DIM + j]) - d);
    }
    #pragma unroll
    for (int o = 1; o < 64; o <<= 1) acc += __shfl_xor(acc, o);
    __shared__ float ws[4];
    if (lane == 0) ws[wave] = acc;
    __syncthreads();
    if (tid == 0)
        atomicAdd(out, (ws[0] + ws[1] + ws[2] + ws[3]) / ((float)m * (float)B));
}

extern "C" void kernel_launch(void* const* d_in, const int* in_sizes, int n_in,
                              void* d_out, int out_size, void* d_ws, size_t ws_size,
                              hipStream_t stream) {
    const float* x  = (const float*)d_in[0];
    const float* y  = (const float*)d_in[1];
    const int* im1  = (const int*)d_in[2];
    const int* im2  = (const int*)d_in[3];
    const int* sh1  = (const int*)d_in[4];
    const int* sh2  = (const int*)d_in[5];

    int B = in_sizes[2] / T_DIM;
    int rows = B * T_DIM;
    size_t nElem = (size_t)rows * D_DIM;

    __hip_bfloat16* xn = (__hip_bfloat16*)d_ws;
    __hip_bfloat16* yn = xn + nElem;
    float* mxf  = (float*)(yn + nElem);
    float* gsum = mxf + (size_t)rows;
    int*   Ridx = (int*)(gsum + rows);
    int*   Cidx = Ridx + rows;
    int*   cnt  = Cidx + rows;

    int normBlocks = 2 * rows / 16;
    prep<<<normBlocks + 2 * B, 256, 0, stream>>>(x, y, im1, sh1, im2, sh2,
                                                 xn, yn, mxf, Ridx, Cidx, cnt,
                                                 gsum, (float*)d_out, rows, normBlocks, B);

    dim3 grid(T_DIM / 64, B, SPLITS);
    ntxent_main<<<grid, 256, 0, stream>>>(xn, yn, mxf, Cidx, cnt, gsum, B);

    dim3 grid2(16, B);
    per_col_loss<<<grid2, 256, 0, stream>>>(xn, yn, gsum, Ridx, Cidx, cnt,
                                            (float*)d_out, B);
}

// Round 5
// 108.407 us; speedup vs baseline: 3.2047x; 1.1126x over previous
//
#include <hip/hip_runtime.h>
#include <hip/hip_bf16.h>
#include <math.h>

#define T_DIM 4096
#define D_DIM 64
#define SPLITS 8
#define SCALE_X 14.4269504088896340736f   // (1/TEMPERATURE) * log2(e): exp(10 s) = exp2(14.427 s)
#define LN2 0.69314718055994530942f

typedef short bfrag8 __attribute__((ext_vector_type(8)));   // 8 bf16 = 4 VGPRs
typedef float floatx4 __attribute__((ext_vector_type(4)));

__device__ __forceinline__ float bf2f(unsigned short u) {
    return __uint_as_float(((unsigned int)u) << 16);
}

// ---------------------------------------------------------------------------
// K1 "prep": fused normalize (blocks [0,normBlocks)) + parallel 2-pass mask
// compaction + gsum/out zeroing (blocks [normBlocks, normBlocks+2B)).
// Normalize: 16 rows/block, 16 lanes/row, float4 loads, ushort4 stores.
// x rows scaled by SCALE_X (folds 1/T and log2(e) into the bf16 cast).
// ---------------------------------------------------------------------------
__launch_bounds__(256)
__global__ void prep(const float* __restrict__ x, const float* __restrict__ y,
                     const int* __restrict__ im1, const int* __restrict__ sh1,
                     const int* __restrict__ im2, const int* __restrict__ sh2,
                     __hip_bfloat16* __restrict__ xn, __hip_bfloat16* __restrict__ yn,
                     int* __restrict__ Ridx, int* __restrict__ Cidx,
                     int* __restrict__ cnt, float* __restrict__ gsum, float* __restrict__ out,
                     int rows, int normBlocks, int B) {
    int tid = threadIdx.x;
    if ((int)blockIdx.x < normBlocks) {
        int row = blockIdx.x * 16 + (tid >> 4);
        int l = tid & 15;
        const float* src; __hip_bfloat16* dst; float scale;
        if (row < rows) { src = x; dst = xn; scale = SCALE_X; }
        else { src = y; dst = yn; scale = 1.0f; row -= rows; }
        size_t off = (size_t)row * D_DIM + l * 4;
        float4 v = *reinterpret_cast<const float4*>(src + off);
        float ss = v.x * v.x + v.y * v.y + v.z * v.z + v.w * v.w;
        #pragma unroll
        for (int o = 1; o < 16; o <<= 1) ss += __shfl_xor(ss, o);
        float inv = scale / fmaxf(sqrtf(ss), 1e-12f);
        __hip_bfloat16 h0 = __float2bfloat16(v.x * inv);
        __hip_bfloat16 h1 = __float2bfloat16(v.y * inv);
        __hip_bfloat16 h2 = __float2bfloat16(v.z * inv);
        __hip_bfloat16 h3 = __float2bfloat16(v.w * inv);
        ushort4 o4;
        o4.x = *reinterpret_cast<unsigned short*>(&h0);
        o4.y = *reinterpret_cast<unsigned short*>(&h1);
        o4.z = *reinterpret_cast<unsigned short*>(&h2);
        o4.w = *reinterpret_cast<unsigned short*>(&h3);
        *reinterpret_cast<ushort4*>((unsigned short*)dst + off) = o4;
    } else {
        int z = blockIdx.x - normBlocks;
        int which = z & 1, b = z >> 1;
        const int* im = which ? im2 : im1;
        const int* sh = which ? sh2 : sh1;
        int* idxout   = which ? Cidx : Ridx;

        // 64 wave-units of 64 elements; wave w owns units w, w+4, ..., w+60.
        __shared__ int cw[64];     // per-unit selected count
        __shared__ int offx[64];   // exclusive prefix
        int w = tid >> 6, lane = tid & 63;
        const int* imb = im + (size_t)b * T_DIM;
        const int* shb = sh + (size_t)b * T_DIM;

        // pass 1: parallel counts (independent loads, fully unrolled)
        #pragma unroll
        for (int k = 0; k < 16; k++) {
            int u = w + k * 4;
            int t = u * 64 + lane;
            int mv = imb[t] * shb[t];
            unsigned long long bal = __ballot(mv != 0);
            if (lane == 0) cw[u] = __popcll(bal);
        }
        __syncthreads();
        // scan 64 counts on wave 0
        if (w == 0) {
            int v = cw[lane];
            int incl = v;
            #pragma unroll
            for (int o = 1; o < 64; o <<= 1) {
                int t = __shfl_up(incl, o);
                if (lane >= o) incl += t;
            }
            offx[lane] = incl - v;
            if (lane == 63) cnt[which * B + b] = incl;
        }
        __syncthreads();
        // pass 2: parallel writes
        #pragma unroll
        for (int k = 0; k < 16; k++) {
            int u = w + k * 4;
            int t = u * 64 + lane;
            int mv = imb[t] * shb[t];
            unsigned long long bal = __ballot(mv != 0);
            int pre = __popcll(bal & ((1ull << lane) - 1ull));
            if (mv) idxout[(size_t)b * T_DIM + offx[u] + pre] = t;
        }
        // zero gsum for this batch (which==0 blocks) + out
        if (which == 0) {
            for (int i = tid; i < T_DIM; i += 256) gsum[(size_t)b * T_DIM + i] = 0.0f;
            if (b == 0 && tid == 0) out[0] = 0.0f;
        }
    }
}

// ---------------------------------------------------------------------------
// K2 main: grid (T/64 col-tiles, B, SPLITS); 256 thr / 4 waves.
// Gathers ONLY selected rows via Ridx (split s handles groups s, s+8, ...):
// gsum[c] += sum_{i<nx} exp2(sim2[R_i][c]), sim2 in log2 units (folded scale).
// Two-level prefetch (indices -> rows); tail rows masked by in-reg weights.
// ---------------------------------------------------------------------------
__launch_bounds__(256)
__global__ void ntxent_main(const __hip_bfloat16* __restrict__ xn,
                            const __hip_bfloat16* __restrict__ yn,
                            const int* __restrict__ Ridx,
                            const int* __restrict__ Cidx,
                            const int* __restrict__ cnt,
                            float* __restrict__ gsum, int B) {
    int b  = blockIdx.y;
    int nx = cnt[b];
    int ny = cnt[B + b];
    int m  = min(nx, ny);
    int j0 = blockIdx.x * 64;
    if (j0 >= m) return;
    int rbase = blockIdx.z * 64;          // stride 64*SPLITS = 512 selected rows

    __shared__ __hip_bfloat16 Bs[64 * 72];   // col-vector stride 144B
    __shared__ int Cloc[64];

    int tid  = threadIdx.x;
    int wave = tid >> 6, lane = tid & 63, quad = lane >> 4, c16 = lane & 15;

    if (tid < 64) {
        int j = j0 + tid;
        Cloc[tid] = (j < ny) ? Cidx[(size_t)b * T_DIM + j] : 0;
    }
    __syncthreads();

    // Stage B tile: 64 col vectors x 128B
    #pragma unroll
    for (int i = tid; i < 64 * 8; i += 256) {
        int c = i >> 3, part = i & 7;
        bfrag8 v = *reinterpret_cast<const bfrag8*>(
            yn + ((size_t)b * T_DIM + Cloc[c]) * D_DIM + part * 8);
        *reinterpret_cast<bfrag8*>(&Bs[c * 72 + part * 8]) = v;
    }
    __syncthreads();

    bfrag8 bf[4][2];
    #pragma unroll
    for (int cg = 0; cg < 4; cg++)
        #pragma unroll
        for (int kh = 0; kh < 2; kh++)
            bf[cg][kh] = *reinterpret_cast<const bfrag8*>(
                &Bs[(cg * 16 + c16) * 72 + kh * 32 + quad * 8]);

    const __hip_bfloat16* xb = xn + (size_t)b * T_DIM * D_DIM;
    const int* Rb = Ridx + (size_t)b * T_DIM;

    float csum[4] = {0.f, 0.f, 0.f, 0.f};

    // prefetch iter 0: index then row (weight-0 rows use row 0, valid)
    int gi = rbase + wave * 16 + c16;
    int idx0 = (gi < nx) ? Rb[gi] : 0;
    const __hip_bfloat16* arow = xb + (size_t)idx0 * D_DIM;
    bfrag8 af0 = *reinterpret_cast<const bfrag8*>(arow + quad * 8);
    bfrag8 af1 = *reinterpret_cast<const bfrag8*>(arow + 32 + quad * 8);

    for (int i0 = rbase; i0 < nx; i0 += 64 * SPLITS) {
        // prefetch next iteration's row (index load is in valid ws memory)
        int gin = i0 + 64 * SPLITS + wave * 16 + c16;
        int idxn = (gin < nx) ? Rb[gin] : 0;
        const __hip_bfloat16* narow = xb + (size_t)idxn * D_DIM;
        bfrag8 naf0 = *reinterpret_cast<const bfrag8*>(narow + quad * 8);
        bfrag8 naf1 = *reinterpret_cast<const bfrag8*>(narow + 32 + quad * 8);

        // tail weights for this iter's 4 output rows
        int grow0 = i0 + wave * 16 + quad * 4;
        float wv[4];
        #pragma unroll
        for (int r = 0; r < 4; r++) wv[r] = (grow0 + r < nx) ? 1.0f : 0.0f;

        #pragma unroll
        for (int cg = 0; cg < 4; cg++) {
            floatx4 acc = {0.f, 0.f, 0.f, 0.f};
            acc = __builtin_amdgcn_mfma_f32_16x16x32_bf16(af0, bf[cg][0], acc, 0, 0, 0);
            acc = __builtin_amdgcn_mfma_f32_16x16x32_bf16(af1, bf[cg][1], acc, 0, 0, 0);
            #pragma unroll
            for (int r = 0; r < 4; r++)
                csum[cg] += wv[r] * exp2f(acc[r]);
        }
        af0 = naf0; af1 = naf1;
    }

    // reduce over quads (rows): lanes differing in bits 4,5 hold same column
    #pragma unroll
    for (int cg = 0; cg < 4; cg++) {
        csum[cg] += __shfl_xor(csum[cg], 16);
        csum[cg] += __shfl_xor(csum[cg], 32);
    }
    if (lane < 16) {
        #pragma unroll
        for (int cg = 0; cg < 4; cg++)
            atomicAdd(&gsum[(size_t)b * T_DIM + j0 + cg * 16 + c16], csum[cg]);
    }
}

// ---------------------------------------------------------------------------
// K3: per-column loss + final mean. Each 16-lane group does one column per
// round: diag2 = dot(xn,yn) (log2 units), per = LN2*(log2(gsum) - diag2).
// Block sum / (m*B) atomicAdd'ed into out[0] (zeroed in prep).
// ---------------------------------------------------------------------------
__launch_bounds__(256)
__global__ void per_col_loss(const __hip_bfloat16* __restrict__ xn,
                             const __hip_bfloat16* __restrict__ yn,
                             const float* __restrict__ gsum,
                             const int* __restrict__ Ridx, const int* __restrict__ Cidx,
                             const int* __restrict__ cnt,
                             float* __restrict__ out, int B) {
    int b  = blockIdx.y;
    int m  = min(cnt[b], cnt[B + b]);
    if (m <= 0) return;

    int tid = threadIdx.x, wave = tid >> 6, lane = tid & 63;
    int g = tid >> 4, l = tid & 15;

    float acc = 0.0f;
    for (int j = blockIdx.x * 16 + g; j < m; j += 16 * gridDim.x) {
        int rj = Ridx[(size_t)b * T_DIM + j];
        int cj = Cidx[(size_t)b * T_DIM + j];
        const unsigned short* xa =
            (const unsigned short*)(xn + ((size_t)b * T_DIM + rj) * D_DIM) + l * 4;
        const unsigned short* yc =
            (const unsigned short*)(yn + ((size_t)b * T_DIM + cj) * D_DIM) + l * 4;
        float d = 0.0f;
        #pragma unroll
        for (int e = 0; e < 4; e++) d += bf2f(xa[e]) * bf2f(yc[e]);
        #pragma unroll
        for (int o = 1; o < 16; o <<= 1) d += __shfl_xor(d, o);
        if (l == 0) acc += LN2 * (__log2f(gsum[(size_t)b * T_DIM + j]) - d);
    }
    #pragma unroll
    for (int o = 1; o < 64; o <<= 1) acc += __shfl_xor(acc, o);
    __shared__ float ws[4];
    if (lane == 0) ws[wave] = acc;
    __syncthreads();
    if (tid == 0)
        atomicAdd(out, (ws[0] + ws[1] + ws[2] + ws[3]) / ((float)m * (float)B));
}

extern "C" void kernel_launch(void* const* d_in, const int* in_sizes, int n_in,
                              void* d_out, int out_size, void* d_ws, size_t ws_size,
                              hipStream_t stream) {
    const float* x  = (const float*)d_in[0];
    const float* y  = (const float*)d_in[1];
    const int* im1  = (const int*)d_in[2];
    const int* im2  = (const int*)d_in[3];
    const int* sh1  = (const int*)d_in[4];
    const int* sh2  = (const int*)d_in[5];

    int B = in_sizes[2] / T_DIM;
    int rows = B * T_DIM;
    size_t nElem = (size_t)rows * D_DIM;

    __hip_bfloat16* xn = (__hip_bfloat16*)d_ws;
    __hip_bfloat16* yn = xn + nElem;
    float* gsum = (float*)(yn + nElem);
    int*   Ridx = (int*)(gsum + rows);
    int*   Cidx = Ridx + rows;
    int*   cnt  = Cidx + rows;

    int normBlocks = 2 * rows / 16;
    prep<<<normBlocks + 2 * B, 256, 0, stream>>>(x, y, im1, sh1, im2, sh2,
                                                 xn, yn, Ridx, Cidx, cnt,
                                                 gsum, (float*)d_out, rows, normBlocks, B);

    dim3 grid(T_DIM / 64, B, SPLITS);
    ntxent_main<<<grid, 256, 0, stream>>>(xn, yn, Ridx, Cidx, cnt, gsum, B);

    dim3 grid2(16, B);
    per_col_loss<<<grid2, 256, 0, stream>>>(xn, yn, gsum, Ridx, Cidx, cnt,
                                            (float*)d_out, B);
}